// Round 3
// baseline (356.097 us; speedup 1.0000x reference)
//
#include <hip/hip_runtime.h>

// z[b,c,m] = sum_d S[m,c,d] * (x[b,d,m] - mean[d,m])
// B=1024, C=64, M=512.  x:(B,C,M) f32, mean:(1,C,M), S:(M,C,C), out:(B,C,M)

namespace {
constexpr int Bb = 1024, Cc = 64, Mm = 512;
constexpr int BT = 64;        // b per block
constexpr int MT = 16;        // m per block (one per wave)
constexpr int DC = 16;        // d per chunk
constexpr int NCH = Cc / DC;  // 4 chunks
constexpr int PAD = 2;
constexpr int RB = BT + PAD;        // 66 floats per (d,m) row -> lane-stride 1, bank-free
constexpr int BUFF = DC * MT * RB;  // 16896 floats per buffer
constexpr size_t LDS_BYTES = 2ull * BUFF * sizeof(float);  // 135168 B

// Stage one (16d x 64b x 16m) chunk of xc = x - mean into registers.
__device__ __forceinline__ void load_chunk(const float* __restrict__ x,
                                           const float* __restrict__ mean,
                                           int b_base, int m_base, int k,
                                           int tid, float4* r) {
  const int q = tid & 3;  // which float4 along m
#pragma unroll
  for (int i = 0; i < 4; ++i) {
    const int row = (tid >> 2) + (i << 8);  // 0..1023 = 16d x 64b
    const int d = row >> 6;
    const int b = row & 63;
    const int gd = k * DC + d;
    const float4 xv = *reinterpret_cast<const float4*>(
        x + (size_t)(((b_base + b) * Cc + gd) * Mm + m_base + q * 4));
    const float4 mv =
        *reinterpret_cast<const float4*>(mean + (size_t)(gd * Mm + m_base + q * 4));
    r[i] = make_float4(xv.x - mv.x, xv.y - mv.y, xv.z - mv.z, xv.w - mv.w);
  }
}

// LDS layout: buf[(d*MT + m)*RB + b].  Scattered b32 writes, conflict-free.
__device__ __forceinline__ void store_chunk(float* __restrict__ buf, int tid,
                                            const float4* r) {
  const int q = tid & 3;
#pragma unroll
  for (int i = 0; i < 4; ++i) {
    const int row = (tid >> 2) + (i << 8);
    const int d = row >> 6;
    const int b = row & 63;
    float* p = &buf[(d * MT + q * 4) * RB + b];
    p[0 * RB] = r[i].x;
    p[1 * RB] = r[i].y;
    p[2 * RB] = r[i].z;
    p[3 * RB] = r[i].w;
  }
}
}  // namespace

__global__ __launch_bounds__(1024, 4) void zca_fwd(
    const float* __restrict__ x, const float* __restrict__ mean,
    const float* __restrict__ S, float* __restrict__ out) {
  extern __shared__ float xs[];  // [2][BUFF]
  const int tid = threadIdx.x;
  const int lane = tid & 63;
  const int q = tid & 3;
  const int w = __builtin_amdgcn_readfirstlane(tid >> 6);  // wave id == m_local

  // XCD-bijective swizzle: 512 blocks, 8 XCDs -> contiguous m-range per XCD
  const int id = blockIdx.x;
  const int sw = ((id & 7) << 6) + (id >> 3);
  const int m_base = (sw >> 4) * MT;
  const int b_base = (sw & 15) * BT;

  float acc[Cc];
#pragma unroll
  for (int c = 0; c < Cc; ++c) acc[c] = 0.f;

  const float* Sm = S + (size_t)(m_base + w) * (Cc * Cc);  // wave-uniform -> s_load

  // --- prologue ---
  float4 st[4];
  load_chunk(x, mean, b_base, m_base, 0, tid, st);
  store_chunk(&xs[0], tid, st);
  load_chunk(x, mean, b_base, m_base, 1, tid, st);
  __syncthreads();

  // --- main loop: double-buffered, 1 barrier per chunk ---
  for (int k = 0; k < NCH; ++k) {
    if (k < NCH - 1) {
      store_chunk(&xs[((k + 1) & 1) * BUFF], tid, st);
      if (k < NCH - 2) load_chunk(x, mean, b_base, m_base, k + 2, tid, st);
    }
    const float* buf = &xs[(k & 1) * BUFF];
    float xv[DC];
#pragma unroll
    for (int j = 0; j < DC; ++j) xv[j] = buf[(j * MT + w) * RB + lane];
    const float* Sk = Sm + k * DC;
#pragma unroll
    for (int c = 0; c < Cc; ++c) {
      float a = acc[c];
#pragma unroll
      for (int j = 0; j < DC; ++j) a = fmaf(Sk[c * Cc + j], xv[j], a);
      acc[c] = a;
    }
    if (k < NCH - 1) __syncthreads();
  }

  // --- epilogue: transpose z through LDS, compile-time cc (keeps acc in VGPRs).
  // z-tile layout: zt[(cl*MT + m)*RB + b]; no extra barriers needed between
  // groups (alternating buffers + the internal barrier order the hazards).
#define EPI(CCg)                                                             \
  {                                                                          \
    float* zt = &xs[((CCg) & 1) * BUFF];                                     \
    _Pragma("unroll") for (int ci = 0; ci < 16; ++ci)                        \
        zt[(ci * MT + w) * RB + lane] = acc[(CCg) * 16 + ci];                \
    __syncthreads();                                                         \
    _Pragma("unroll") for (int i = 0; i < 4; ++i) {                          \
      const int row = (tid >> 2) + (i << 8); /* 16cl x 64b */                \
      const int cl = row >> 6;                                               \
      const int b = row & 63;                                                \
      const float* p = &zt[(cl * MT + q * 4) * RB + b];                      \
      const float4 v = make_float4(p[0 * RB], p[1 * RB], p[2 * RB], p[3 * RB]); \
      *reinterpret_cast<float4*>(                                            \
          &out[(size_t)(((b_base + b) * Cc + (CCg) * 16 + cl) * Mm + m_base + \
                        q * 4)]) = v;                                        \
    }                                                                        \
  }
  EPI(0)
  EPI(1)
  EPI(2)
  EPI(3)
#undef EPI
}

extern "C" void kernel_launch(void* const* d_in, const int* in_sizes, int n_in,
                              void* d_out, int out_size, void* d_ws,
                              size_t ws_size, hipStream_t stream) {
  const float* x = (const float*)d_in[0];
  const float* mean = (const float*)d_in[1];
  const float* S = (const float*)d_in[2];
  float* out = (float*)d_out;
  const int nblocks = (Bb / BT) * (Mm / MT);  // 512
  hipLaunchKernelGGL(zca_fwd, dim3(nblocks), dim3(1024), LDS_BYTES, stream, x,
                     mean, S, out);
}

// Round 4
// 97.072 us; speedup vs baseline: 3.6684x; 3.6684x over previous
//
#include <hip/hip_runtime.h>

// z[b,c,m] = sum_d S[m,c,d] * (x[b,d,m] - mean[d,m])
// B=1024, C=64, M=512. x:(B,C,M) f32, mean:(1,C,M), S:(M,C,C), out:(B,C,M) f32
//
// MFMA formulation, per m: Z_m(64c x 64b-tile) = S_m(64x64) @ Xc_m(64d x b)
// using v_mfma_f32_16x16x32_bf16.  A = S chunk [16c x 32d], B = Xc [32d x 16b].
// Layouts (gfx950): A: lane l -> A[l&15][(l>>4)*8+j]; B: lane l -> B[(l>>4)*8+j][l&15];
// D: lane l -> D[(l>>4)*4+r][l&15]  (C/D verified in guide m89/m91).

typedef __attribute__((ext_vector_type(8))) short short8;
typedef __attribute__((ext_vector_type(4))) float f32x4;

namespace {
constexpr int Mm = 512, Cc = 64, Bb = 1024;
constexpr int MT = 16;  // m per block (1 per wave)
constexpr int BT = 32;  // b per block
// x LDS: 512 rows (m*32+b) x 64 bf16 (d), 16B-chunk XOR swizzle -> 64 KB
// z LDS: 1024 rows (cl*32+b) x 17 f32 (16m + pad) -> 69632 B (reuses same space)
constexpr size_t LDSB = 1024 * 17 * 4;

__device__ __forceinline__ unsigned short f2bf(float x) {  // RNE f32->bf16
  unsigned u = __float_as_uint(x);
  u = (u + 0x7fffu + ((u >> 16) & 1u)) >> 16;
  return (unsigned short)u;
}
}  // namespace

__global__ __launch_bounds__(1024, 4) void zca_mfma(
    const float* __restrict__ x, const float* __restrict__ mean,
    const float* __restrict__ S, float* __restrict__ out) {
  extern __shared__ char lds_raw[];
  unsigned short* xl = (unsigned short*)lds_raw;  // bf16 elements
  float* zl = (float*)lds_raw;

  const int tid = threadIdx.x;
  const int lane = tid & 63;
  const int w = __builtin_amdgcn_readfirstlane(tid >> 6);  // wave id = m_local

  // bijective XCD swizzle: 1024 blocks, 8 XCDs, contiguous m-range per XCD
  const int id = blockIdx.x;
  const int sw = ((id & 7) << 7) + (id >> 3);
  const int m0 = (sw >> 5) * MT;
  const int b0 = (sw & 31) * BT;

  // ---- stage (x - mean) -> bf16 LDS [m][b][d], XOR-swizzled 16B chunks ----
  const int mq = tid & 3;    // m-quarter (float4 along m)
  const int rs = tid >> 2;   // 0..255
  const int d = rs & 63;     // constant per thread across passes
  const float4 mv = *(const float4*)(mean + (size_t)d * Mm + m0 + mq * 4);
  float4 xv[8];
#pragma unroll
  for (int p = 0; p < 8; ++p) {
    const int b = p * 4 + (rs >> 6);
    xv[p] = *(const float4*)(x + (size_t)((b0 + b) * Cc + d) * Mm + m0 + mq * 4);
  }
#pragma unroll
  for (int p = 0; p < 8; ++p) {
    const int b = p * 4 + (rs >> 6);
    const float v[4] = {xv[p].x - mv.x, xv[p].y - mv.y, xv[p].z - mv.z,
                        xv[p].w - mv.w};
#pragma unroll
    for (int i = 0; i < 4; ++i) {
      const int row = (mq * 4 + i) * BT + b;  // m_loc*32 + b
      const int idx = row * 64 + (((d >> 3) ^ (row & 7)) << 3) + (d & 7);
      xl[idx] = f2bf(v[i]);
    }
  }

  // ---- A fragments: S[m] f32 -> bf16 in regs (L2-resident per XCD) ----
  const int m = m0 + w;
  short8 A[4][2];
#pragma unroll
  for (int ct = 0; ct < 4; ++ct) {
#pragma unroll
    for (int ks = 0; ks < 2; ++ks) {
      const float* sp = S + ((size_t)m * Cc + ct * 16 + (lane & 15)) * Cc +
                        ks * 32 + (lane >> 4) * 8;
      const float4 f0 = *(const float4*)sp;
      const float4 f1 = *(const float4*)(sp + 4);
      short8 a;
      a[0] = (short)f2bf(f0.x); a[1] = (short)f2bf(f0.y);
      a[2] = (short)f2bf(f0.z); a[3] = (short)f2bf(f0.w);
      a[4] = (short)f2bf(f1.x); a[5] = (short)f2bf(f1.y);
      a[6] = (short)f2bf(f1.z); a[7] = (short)f2bf(f1.w);
      A[ct][ks] = a;
    }
  }

  __syncthreads();  // x tile ready

  // ---- B fragments from LDS + 16 MFMAs ----
  short8 Bf[2][2];
#pragma unroll
  for (int bs = 0; bs < 2; ++bs) {
#pragma unroll
    for (int ks = 0; ks < 2; ++ks) {
      const int row = w * BT + bs * 16 + (lane & 15);
      const int chunk = ks * 4 + (lane >> 4);
      const int idx = row * 64 + ((chunk ^ (row & 7)) << 3);
      Bf[bs][ks] = *(const short8*)(xl + idx);
    }
  }

  f32x4 acc[4][2];
#pragma unroll
  for (int ct = 0; ct < 4; ++ct)
#pragma unroll
    for (int bs = 0; bs < 2; ++bs) acc[ct][bs] = (f32x4){0.f, 0.f, 0.f, 0.f};

#pragma unroll
  for (int ks = 0; ks < 2; ++ks)
#pragma unroll
    for (int ct = 0; ct < 4; ++ct)
#pragma unroll
      for (int bs = 0; bs < 2; ++bs)
        acc[ct][bs] = __builtin_amdgcn_mfma_f32_16x16x32_bf16(
            A[ct][ks], Bf[bs][ks], acc[ct][bs], 0, 0, 0);

  __syncthreads();  // all x reads done; z-tile may overwrite

  // ---- epilogue: two c-half transposes through LDS, 64B-contig stores ----
#pragma unroll
  for (int h = 0; h < 2; ++h) {
#pragma unroll
    for (int cb = 0; cb < 2; ++cb) {
#pragma unroll
      for (int bs = 0; bs < 2; ++bs) {
#pragma unroll
        for (int r = 0; r < 4; ++r) {
          const int cl = cb * 16 + (lane >> 4) * 4 + r;  // 0..31 in half
          const int b = bs * 16 + (lane & 15);
          const int row = cl * BT + b;
          const int col = w ^ (cl & 12);  // bank swizzle, float4-safe
          zl[row * 17 + col] = acc[2 * h + cb][bs][r];
        }
      }
    }
    __syncthreads();
#pragma unroll
    for (int p = 0; p < 4; ++p) {
      const int row = p * 256 + rs;
      const int cl = row >> 5, b = row & 31;
      const int colq = mq ^ ((cl >> 2) & 3);
      const float4 v = *(const float4*)(zl + row * 17 + colq * 4);
      *(float4*)(out +
                 (size_t)((b0 + b) * Cc + h * 32 + cl) * Mm + m0 + mq * 4) = v;
    }
    if (h == 0) __syncthreads();
  }
}

extern "C" void kernel_launch(void* const* d_in, const int* in_sizes, int n_in,
                              void* d_out, int out_size, void* d_ws,
                              size_t ws_size, hipStream_t stream) {
  const float* x = (const float*)d_in[0];
  const float* mean = (const float*)d_in[1];
  const float* S = (const float*)d_in[2];
  float* out = (float*)d_out;
  const int nblocks = (Bb / BT) * (Mm / MT);  // 32 * 32 = 1024
  hipLaunchKernelGGL(zca_mfma, dim3(nblocks), dim3(1024), LDSB, stream, x,
                     mean, S, out);
}